// Round 3
// baseline (438.176 us; speedup 1.0000x reference)
//
#include <hip/hip_runtime.h>
#include <hip/hip_bf16.h>

static constexpr int B_ = 256;
static constexpr int R_ = 1152;
static constexpr int C_ = 10;
static constexpr int O_ = 16;
static constexpr int I_ = 8;
static constexpr int SCO = C_ * O_;   // 160
static constexpr int NV = B_ * SCO;   // 40960 (also the output size, (B,C,O,1))

__device__ __forceinline__ float dot8(const float* a, const float* b) {
  float d = a[0] * b[0];
  d = fmaf(a[1], b[1], d); d = fmaf(a[2], b[2], d); d = fmaf(a[3], b[3], d);
  d = fmaf(a[4], b[4], d); d = fmaf(a[5], b[5], d); d = fmaf(a[6], b[6], d);
  d = fmaf(a[7], b[7], d);
  return d;
}

// partial[seg][b][c][o] = sum_{r in seg's chunks} c[r,c] * (W[r,c,o,:] . x[b,r,:])
// grid = nseg*C_, 256 threads; wave -> o-quad (o0 = (t>>6)*4), lane -> 4 b's.
// Deterministic: each block owns its (seg,c) slice of `partial`; no atomics.
__global__ __launch_bounds__(256) void k_s(const float* __restrict__ x,
                                           const float* __restrict__ W,
                                           const float* __restrict__ cvec,
                                           float* __restrict__ partial,
                                           int use_c, int nseg) {
  __shared__ float Wl[18 * 128];   // W[r0..r0+17, c, :, :] as [rr][o*8+i]
  __shared__ float cwl[18];
  const int c   = blockIdx.x % C_;
  const int seg = blockIdx.x / C_;
  const int chunks = 64 / nseg;    // nseg*chunks*18 == 1152
  const int t  = threadIdx.x;
  const int b0 = (t & 63) * 4;
  const int o0 = (t >> 6) * 4;

  float acc[4][4] = {};
  for (int ch = 0; ch < chunks; ++ch) {
    const int r0 = (seg * chunks + ch) * 18;
    __syncthreads();               // protect Wl against readers of previous chunk
    for (int e = t; e < 18 * 128; e += 256) {
      int rr = e >> 7, j = e & 127;
      Wl[e] = W[((size_t)((r0 + rr) * C_ + c)) * 128 + j];
    }
    if (t < 18) cwl[t] = use_c ? cvec[(r0 + t) * C_ + c] : (1.0f / 1152.0f);
    __syncthreads();

    for (int rr = 0; rr < 18; ++rr) {
      const float cw = cwl[rr];
      const float* wb = &Wl[rr * 128 + o0 * 8];
      float wf[4][8];
#pragma unroll
      for (int oo = 0; oo < 4; ++oo)
#pragma unroll
        for (int i = 0; i < 8; ++i) wf[oo][i] = wb[oo * 8 + i];
#pragma unroll
      for (int bb = 0; bb < 4; ++bb) {
        const float4* xp = (const float4*)(x + ((size_t)(b0 + bb) * R_ + (r0 + rr)) * I_);
        float4 x0 = xp[0], x1 = xp[1];
        float xf[8] = {x0.x, x0.y, x0.z, x0.w, x1.x, x1.y, x1.z, x1.w};
#pragma unroll
        for (int oo = 0; oo < 4; ++oo) {
          float d = dot8(wf[oo], xf);
          acc[bb][oo] = fmaf(cw, d, acc[bb][oo]);
        }
      }
    }
  }
  float* pp = partial + (size_t)seg * NV;
#pragma unroll
  for (int bb = 0; bb < 4; ++bb)
#pragma unroll
    for (int oo = 0; oo < 4; ++oo)
      pp[(size_t)(b0 + bb) * SCO + c * O_ + o0 + oo] = acc[bb][oo];
}

// s = sum over segment partials; squash v = s*|s|/(1+s^2)
// (== s^3/((1+s^2)*sqrt(s^2)) for s != 0; division-safe everywhere)
__global__ __launch_bounds__(256) void k_sv(const float* __restrict__ partial,
                                            float* __restrict__ v, int nseg) {
  const int i = blockIdx.x * 256 + threadIdx.x;  // < NV
  float s = 0.0f;
  for (int g = 0; g < nseg; ++g) s += partial[(size_t)g * NV + i];
  v[i] = s * fabsf(s) / (1.0f + s * s);
}

// bsum[r,c] = sum_b sum_o (W[r,c,o,:].x[b,r,:]) * v[b,c,o]
// grid = R_ blocks; lane -> 4 b's; wave w -> c in {w, w+4, w+8} (uniform trip count).
__global__ __launch_bounds__(256) void k_a(const float* __restrict__ x,
                                           const float* __restrict__ W,
                                           const float* __restrict__ v,
                                           float* __restrict__ bsum) {
  __shared__ float Wl[C_ * O_ * I_];  // 1280 floats, [c][o][i]
  const int r = blockIdx.x;
  const int t = threadIdx.x;
  for (int e = t; e < C_ * O_ * I_; e += 256)
    Wl[e] = W[(size_t)r * (C_ * O_ * I_) + e];
  __syncthreads();

  const int lane = t & 63;
  const int w    = t >> 6;
  const int b0   = lane * 4;

  float xf[4][8];
#pragma unroll
  for (int bb = 0; bb < 4; ++bb) {
    const float4* xp = (const float4*)(x + ((size_t)(b0 + bb) * R_ + r) * I_);
    float4 x0 = xp[0], x1 = xp[1];
    xf[bb][0] = x0.x; xf[bb][1] = x0.y; xf[bb][2] = x0.z; xf[bb][3] = x0.w;
    xf[bb][4] = x1.x; xf[bb][5] = x1.y; xf[bb][6] = x1.z; xf[bb][7] = x1.w;
  }

  for (int c = w; c < C_; c += 4) {
    float a = 0.0f;
#pragma unroll
    for (int bb = 0; bb < 4; ++bb) {
      const float4* vp = (const float4*)(v + (size_t)(b0 + bb) * SCO + c * O_);
#pragma unroll
      for (int q = 0; q < 4; ++q) {
        float4 vv = vp[q];
        const float* w0 = &Wl[(c * O_ + q * 4) * I_];
        a = fmaf(dot8(w0,      xf[bb]), vv.x, a);
        a = fmaf(dot8(w0 + 8,  xf[bb]), vv.y, a);
        a = fmaf(dot8(w0 + 16, xf[bb]), vv.z, a);
        a = fmaf(dot8(w0 + 24, xf[bb]), vv.w, a);
      }
    }
    a += __shfl_xor(a, 1);  a += __shfl_xor(a, 2);  a += __shfl_xor(a, 4);
    a += __shfl_xor(a, 8);  a += __shfl_xor(a, 16); a += __shfl_xor(a, 32);
    if (lane == 0) bsum[(size_t)r * C_ + c] = a;
  }
}

// b_new = (first ? 0 : b_prev) + bsum/256; cvec = softmax over r per c. grid = C_.
__global__ __launch_bounds__(256) void k_bc(const float* __restrict__ bsum,
                                            float* __restrict__ bvec,
                                            float* __restrict__ cvec, int first) {
  const int c = blockIdx.x;
  const int t = threadIdx.x;
  __shared__ float smx[4];
  __shared__ float sms[4];
  float bv[5];
  float mx = -3.402823466e38f;
#pragma unroll
  for (int k = 0; k < 5; ++k) {
    int r = t + k * 256;
    if (r < R_) {
      float val = bsum[r * C_ + c] * (1.0f / 256.0f);
      if (!first) val += bvec[r * C_ + c];
      bvec[r * C_ + c] = val;
      bv[k] = val;
      mx = fmaxf(mx, val);
    }
  }
  mx = fmaxf(mx, __shfl_xor(mx, 1));  mx = fmaxf(mx, __shfl_xor(mx, 2));
  mx = fmaxf(mx, __shfl_xor(mx, 4));  mx = fmaxf(mx, __shfl_xor(mx, 8));
  mx = fmaxf(mx, __shfl_xor(mx, 16)); mx = fmaxf(mx, __shfl_xor(mx, 32));
  if ((t & 63) == 0) smx[t >> 6] = mx;
  __syncthreads();
  float MX = fmaxf(fmaxf(smx[0], smx[1]), fmaxf(smx[2], smx[3]));
  float se = 0.0f;
  float ef[5];
#pragma unroll
  for (int k = 0; k < 5; ++k) {
    int r = t + k * 256;
    if (r < R_) { ef[k] = expf(bv[k] - MX); se += ef[k]; }
  }
  se += __shfl_xor(se, 1);  se += __shfl_xor(se, 2);  se += __shfl_xor(se, 4);
  se += __shfl_xor(se, 8);  se += __shfl_xor(se, 16); se += __shfl_xor(se, 32);
  if ((t & 63) == 0) sms[t >> 6] = se;
  __syncthreads();
  float inv = 1.0f / ((sms[0] + sms[1]) + (sms[2] + sms[3]));
#pragma unroll
  for (int k = 0; k < 5; ++k) {
    int r = t + k * 256;
    if (r < R_) cvec[r * C_ + c] = ef[k] * inv;
  }
}

extern "C" void kernel_launch(void* const* d_in, const int* in_sizes, int n_in,
                              void* d_out, int out_size, void* d_ws, size_t ws_size,
                              hipStream_t stream) {
  const float* x = (const float*)d_in[0];  // (B,R,I) fp32
  const float* W = (const float*)d_in[1];  // (R,C,O,I) fp32
  float* out = (float*)d_out;              // (B,C,O,1) fp32, NV elements
  float* ws = (float*)d_ws;

  // ws-adaptive segment count: tail (v,bvec,cvec,bsum) + nseg partial buffers
  const long availf = (long)(ws_size / 4);
  const long fixedf = NV + 3L * (R_ * C_);
  long cap = (availf - fixedf) / NV;
  int nseg = 1;
  while (nseg * 2 <= 64 && (long)(nseg * 2) <= cap) nseg *= 2;

  float* partial = ws;
  float* v    = partial + (size_t)nseg * NV;
  float* bvec = v + NV;
  float* cvec = bvec + (R_ * C_);
  float* bsum = cvec + (R_ * C_);

  for (int it = 0; it < 3; ++it) {
    k_s<<<nseg * C_, 256, 0, stream>>>(x, W, cvec, partial, it > 0 ? 1 : 0, nseg);
    // final iteration squashes straight into d_out
    k_sv<<<NV / 256, 256, 0, stream>>>(partial, (it == 2) ? out : v, nseg);
    if (it < 2) {
      k_a<<<R_, 256, 0, stream>>>(x, W, v, bsum);
      k_bc<<<C_, 256, 0, stream>>>(bsum, bvec, cvec, it == 0 ? 1 : 0);
    }
  }
}

// Round 4
// 352.660 us; speedup vs baseline: 1.2425x; 1.2425x over previous
//
#include <hip/hip_runtime.h>

static constexpr int B_ = 256;
static constexpr int R_ = 1152;
static constexpr int C_ = 10;
static constexpr int O_ = 16;
static constexpr int I_ = 8;
static constexpr int SCO = C_ * O_;   // 160
static constexpr int NV = B_ * SCO;   // 40960 (= output size, (B,C,O,1))

__device__ __forceinline__ float dot8v(const float* w, float4 a, float4 b) {
  float d = w[0] * a.x;
  d = fmaf(w[1], a.y, d); d = fmaf(w[2], a.z, d); d = fmaf(w[3], a.w, d);
  d = fmaf(w[4], b.x, d); d = fmaf(w[5], b.y, d); d = fmaf(w[6], b.z, d);
  d = fmaf(w[7], b.w, d);
  return d;
}

// partial[seg][b][c][o] += over seg's r-range of c[r,c] * (W[r,c,o,:] . x[b,r,:])
// Block = (seg, bgroup, chalf): lane = b (64 b's), wave = o-quad, 5 c's inside.
// x kept in regs (prefetch 1 r ahead); W/cvec wave-uniform -> scalar loads.
// grid = nseg*8. Deterministic, no atomics.
__global__ __launch_bounds__(256) void k_s(const float* __restrict__ x,
                                           const float* __restrict__ W,
                                           const float* __restrict__ cvec,
                                           float* __restrict__ partial,
                                           int use_c, int nseg) {
  const int bx  = blockIdx.x;
  const int seg = bx >> 3;
  const int bg  = bx & 3;
  const int cg  = (bx >> 2) & 1;
  const int t    = threadIdx.x;
  const int lane = t & 63;
  const int w    = __builtin_amdgcn_readfirstlane(t >> 6);
  const int b  = bg * 64 + lane;
  const int o0 = w * 4;
  const int c0 = cg * 5;
  const int RT = R_ / nseg;          // contiguous r's per segment
  const int rbase = seg * RT;

  const float4* xp = (const float4*)(x + ((size_t)b * R_ + rbase) * I_);
  float4 xa = xp[0], xb = xp[1];
  float acc[5][4] = {};
  for (int rr = 0; rr < RT; ++rr) {
    const int r = rbase + rr;
    float4 na = xa, nb = xb;
    if (rr + 1 < RT) { na = xp[2 * (rr + 1)]; nb = xp[2 * (rr + 1) + 1]; }
#pragma unroll
    for (int cc = 0; cc < 5; ++cc) {
      const int c = c0 + cc;
      const float cw = use_c ? cvec[r * C_ + c] : (1.0f / 1152.0f);
      const float* wr = W + (size_t)(r * C_ + c) * 128 + o0 * 8;  // wave-uniform
      acc[cc][0] = fmaf(cw, dot8v(wr,      xa, xb), acc[cc][0]);
      acc[cc][1] = fmaf(cw, dot8v(wr + 8,  xa, xb), acc[cc][1]);
      acc[cc][2] = fmaf(cw, dot8v(wr + 16, xa, xb), acc[cc][2]);
      acc[cc][3] = fmaf(cw, dot8v(wr + 24, xa, xb), acc[cc][3]);
    }
    xa = na; xb = nb;
  }
  float* pp = partial + (size_t)seg * NV + (size_t)b * SCO;
#pragma unroll
  for (int cc = 0; cc < 5; ++cc) {
    float4 vv = make_float4(acc[cc][0], acc[cc][1], acc[cc][2], acc[cc][3]);
    *(float4*)(pp + (c0 + cc) * O_ + o0) = vv;
  }
}

// s = sum over segment partials; squash v = s*|s|/(1+s^2)
// (== s^3/((1+s^2)*sqrt(s^2)) for s != 0; division-safe everywhere)
__global__ __launch_bounds__(256) void k_sv(const float* __restrict__ partial,
                                            float* __restrict__ v, int nseg) {
  const int i = blockIdx.x * 256 + threadIdx.x;  // < NV
  float s = 0.0f;
  for (int g = 0; g < nseg; ++g) s += partial[(size_t)g * NV + i];
  v[i] = s * fabsf(s) / (1.0f + s * s);
}

// bpart[bg][r][c] = sum_{b in bg} sum_o (W[r,c,o,:].x[b,r,:]) * v[b,c,o]
// Block = (seg of 9 r's, bgroup, chalf); lane = b, wave = o-quad.
// grid = 128*8 = 1024 blocks.
__global__ __launch_bounds__(256) void k_a(const float* __restrict__ x,
                                           const float* __restrict__ W,
                                           const float* __restrict__ v,
                                           float* __restrict__ bpart) {
  __shared__ float red[9 * 5 * 4];
  const int bx  = blockIdx.x;
  const int seg = bx >> 3;
  const int bg  = bx & 3;
  const int cg  = (bx >> 2) & 1;
  const int t    = threadIdx.x;
  const int lane = t & 63;
  const int w    = __builtin_amdgcn_readfirstlane(t >> 6);
  const int b  = bg * 64 + lane;
  const int o0 = w * 4;
  const int c0 = cg * 5;
  const int rbase = seg * 9;

  float4 vf[5];
#pragma unroll
  for (int cc = 0; cc < 5; ++cc)
    vf[cc] = *(const float4*)(v + (size_t)b * SCO + (c0 + cc) * O_ + o0);

  const float4* xp = (const float4*)(x + ((size_t)b * R_ + rbase) * I_);
  float4 xa = xp[0], xb = xp[1];
  for (int rr = 0; rr < 9; ++rr) {
    const int r = rbase + rr;
    float4 na = xa, nb = xb;
    if (rr + 1 < 9) { na = xp[2 * (rr + 1)]; nb = xp[2 * (rr + 1) + 1]; }
#pragma unroll
    for (int cc = 0; cc < 5; ++cc) {
      const float* wr = W + (size_t)(r * C_ + c0 + cc) * 128 + o0 * 8;  // uniform
      float a;
      a = dot8v(wr,      xa, xb) * vf[cc].x;
      a = fmaf(dot8v(wr + 8,  xa, xb), vf[cc].y, a);
      a = fmaf(dot8v(wr + 16, xa, xb), vf[cc].z, a);
      a = fmaf(dot8v(wr + 24, xa, xb), vf[cc].w, a);
      a += __shfl_xor(a, 1);  a += __shfl_xor(a, 2);  a += __shfl_xor(a, 4);
      a += __shfl_xor(a, 8);  a += __shfl_xor(a, 16); a += __shfl_xor(a, 32);
      if (lane == 0) red[(rr * 5 + cc) * 4 + w] = a;
    }
    xa = na; xb = nb;
  }
  __syncthreads();
  if (t < 45) {
    float s = red[t * 4] + red[t * 4 + 1] + red[t * 4 + 2] + red[t * 4 + 3];
    int rr = t / 5, cc = t % 5;
    bpart[((size_t)bg * R_ + (rbase + rr)) * C_ + c0 + cc] = s;
  }
}

// b_new = (first ? 0 : b_prev) + (sum_bg bpart)/256; cvec = softmax over r per c.
__global__ __launch_bounds__(256) void k_bc(const float* __restrict__ bpart,
                                            float* __restrict__ bvec,
                                            float* __restrict__ cvec, int first) {
  const int c = blockIdx.x;
  const int t = threadIdx.x;
  __shared__ float smx[4];
  __shared__ float sms[4];
  float bv[5];
  float mx = -3.402823466e38f;
#pragma unroll
  for (int k = 0; k < 5; ++k) {
    int r = t + k * 256;
    if (r < R_) {
      float s = bpart[(size_t)r * C_ + c]
              + bpart[((size_t)R_ + r) * C_ + c]
              + bpart[((size_t)2 * R_ + r) * C_ + c]
              + bpart[((size_t)3 * R_ + r) * C_ + c];
      float val = s * (1.0f / 256.0f);
      if (!first) val += bvec[r * C_ + c];
      bvec[r * C_ + c] = val;
      bv[k] = val;
      mx = fmaxf(mx, val);
    }
  }
  mx = fmaxf(mx, __shfl_xor(mx, 1));  mx = fmaxf(mx, __shfl_xor(mx, 2));
  mx = fmaxf(mx, __shfl_xor(mx, 4));  mx = fmaxf(mx, __shfl_xor(mx, 8));
  mx = fmaxf(mx, __shfl_xor(mx, 16)); mx = fmaxf(mx, __shfl_xor(mx, 32));
  if ((t & 63) == 0) smx[t >> 6] = mx;
  __syncthreads();
  float MX = fmaxf(fmaxf(smx[0], smx[1]), fmaxf(smx[2], smx[3]));
  float se = 0.0f;
  float ef[5];
#pragma unroll
  for (int k = 0; k < 5; ++k) {
    int r = t + k * 256;
    if (r < R_) { ef[k] = expf(bv[k] - MX); se += ef[k]; }
  }
  se += __shfl_xor(se, 1);  se += __shfl_xor(se, 2);  se += __shfl_xor(se, 4);
  se += __shfl_xor(se, 8);  se += __shfl_xor(se, 16); se += __shfl_xor(se, 32);
  if ((t & 63) == 0) sms[t >> 6] = se;
  __syncthreads();
  float inv = 1.0f / ((sms[0] + sms[1]) + (sms[2] + sms[3]));
#pragma unroll
  for (int k = 0; k < 5; ++k) {
    int r = t + k * 256;
    if (r < R_) cvec[r * C_ + c] = ef[k] * inv;
  }
}

extern "C" void kernel_launch(void* const* d_in, const int* in_sizes, int n_in,
                              void* d_out, int out_size, void* d_ws, size_t ws_size,
                              hipStream_t stream) {
  const float* x = (const float*)d_in[0];  // (B,R,I) fp32
  const float* W = (const float*)d_in[1];  // (R,C,O,I) fp32
  float* out = (float*)d_out;              // (B,C,O,1) fp32, NV elements
  float* ws = (float*)d_ws;

  // ws-adaptive segment count for k_s partials
  const long availf = (long)(ws_size / 4);
  const long fixedf = NV + 6L * (R_ * C_);   // v + bvec + cvec + bpart[4]
  long cap = (availf - fixedf) / NV;
  int nseg = 1;
  while (nseg * 2 <= 64 && (long)(nseg * 2) <= cap) nseg *= 2;

  float* partial = ws;
  float* v     = partial + (size_t)nseg * NV;
  float* bvec  = v + NV;
  float* cvec  = bvec + (R_ * C_);
  float* bpart = cvec + (R_ * C_);

  for (int it = 0; it < 3; ++it) {
    k_s<<<nseg * 8, 256, 0, stream>>>(x, W, cvec, partial, it > 0 ? 1 : 0, nseg);
    k_sv<<<NV / 256, 256, 0, stream>>>(partial, (it == 2) ? out : v, nseg);
    if (it < 2) {
      k_a<<<128 * 8, 256, 0, stream>>>(x, W, v, bpart);
      k_bc<<<C_, 256, 0, stream>>>(bpart, bvec, cvec, it == 0 ? 1 : 0);
    }
  }
}

// Round 5
// 272.854 us; speedup vs baseline: 1.6059x; 1.2925x over previous
//
#include <hip/hip_runtime.h>

static constexpr int B_ = 256;
static constexpr int R_ = 1152;
static constexpr int C_ = 10;
static constexpr int O_ = 16;
static constexpr int I_ = 8;
static constexpr int SCO = C_ * O_;   // 160
static constexpr int NV = B_ * SCO;   // 40960 (= output size, (B,C,O,1))

__device__ __forceinline__ float dot8v(const float* w, float4 a, float4 b) {
  float d = w[0] * a.x;
  d = fmaf(w[1], a.y, d); d = fmaf(w[2], a.z, d); d = fmaf(w[3], a.w, d);
  d = fmaf(w[4], b.x, d); d = fmaf(w[5], b.y, d); d = fmaf(w[6], b.z, d);
  d = fmaf(w[7], b.w, d);
  return d;
}

// partial[seg][b][c][o] = sum_{r in seg} c[r,c] * (W[r,c,o,:] . x[b,r,:])
// Block = (seg, bg, cq): lane = b, wave = o-quad, 2 c's per block.
// XCD swizzle: same-seg blocks co-locate on one XCD (seg = grp*8 + id&7).
// grid = nseg*20. Deterministic, no atomics.
__global__ __launch_bounds__(256) void k_s(const float* __restrict__ x,
                                           const float* __restrict__ W,
                                           const float* __restrict__ cvec,
                                           float* __restrict__ partial,
                                           int use_c, int nseg) {
  int seg, sub;
  if ((nseg & 7) == 0) {
    const int xcd  = blockIdx.x & 7;
    const int rest = blockIdx.x >> 3;
    sub = rest % 20;
    seg = (rest / 20) * 8 + xcd;
  } else {
    seg = blockIdx.x / 20;
    sub = blockIdx.x % 20;
  }
  const int bg = sub & 3;
  const int cq = sub >> 2;           // 0..4
  const int t    = threadIdx.x;
  const int lane = t & 63;
  const int w    = __builtin_amdgcn_readfirstlane(t >> 6);
  const int b  = bg * 64 + lane;
  const int o0 = w * 4;
  const int c0 = cq * 2;
  const int RT = R_ / nseg;
  const int rbase = seg * RT;

  const float4* xp = (const float4*)(x + ((size_t)b * R_ + rbase) * I_);
  float4 xa = xp[0], xb = xp[1];
  float acc[2][4] = {};
  for (int rr = 0; rr < RT; ++rr) {
    const int r = rbase + rr;
    float4 na = xa, nb = xb;
    if (rr + 1 < RT) { na = xp[2 * (rr + 1)]; nb = xp[2 * (rr + 1) + 1]; }
#pragma unroll
    for (int cc = 0; cc < 2; ++cc) {
      const int c = c0 + cc;
      const float cw = use_c ? cvec[r * C_ + c] : (1.0f / 1152.0f);
      const float* wr = W + (size_t)(r * C_ + c) * 128 + o0 * 8;  // wave-uniform
      acc[cc][0] = fmaf(cw, dot8v(wr,      xa, xb), acc[cc][0]);
      acc[cc][1] = fmaf(cw, dot8v(wr + 8,  xa, xb), acc[cc][1]);
      acc[cc][2] = fmaf(cw, dot8v(wr + 16, xa, xb), acc[cc][2]);
      acc[cc][3] = fmaf(cw, dot8v(wr + 24, xa, xb), acc[cc][3]);
    }
    xa = na; xb = nb;
  }
  float* pp = partial + (size_t)seg * NV + (size_t)b * SCO;
#pragma unroll
  for (int cc = 0; cc < 2; ++cc) {
    float4 vv = make_float4(acc[cc][0], acc[cc][1], acc[cc][2], acc[cc][3]);
    *(float4*)(pp + (c0 + cc) * O_ + o0) = vv;
  }
}

// s = sum over segment partials; squash v = s*|s|/(1+s^2)
// (== s^3/((1+s^2)*sqrt(s^2)) for s != 0; division-safe everywhere)
__global__ __launch_bounds__(256) void k_sv(const float* __restrict__ partial,
                                            float* __restrict__ v, int nseg) {
  const int i = blockIdx.x * 256 + threadIdx.x;  // < NV
  float s = 0.0f;
  for (int g = 0; g < nseg; ++g) s += partial[(size_t)g * NV + i];
  v[i] = s * fabsf(s) / (1.0f + s * s);
}

// bpart[bg][r][c] = sum_{b in bg} sum_o (W[r,c,o,:].x[b,r,:]) * v[b,c,o]
// Block = (rseg of 9 r's, bg, cq of 2 c's); lane = b, wave = o-quad.
// grid = 128*20 = 2560 blocks, XCD-swizzled on rseg.
__global__ __launch_bounds__(256) void k_a(const float* __restrict__ x,
                                           const float* __restrict__ W,
                                           const float* __restrict__ v,
                                           float* __restrict__ bpart) {
  __shared__ float red[9 * 2 * 4];
  const int xcd  = blockIdx.x & 7;
  const int rest = blockIdx.x >> 3;
  const int sub  = rest % 20;
  const int rseg = (rest / 20) * 8 + xcd;   // 0..127
  const int bg = sub & 3;
  const int cq = sub >> 2;
  const int t    = threadIdx.x;
  const int lane = t & 63;
  const int w    = __builtin_amdgcn_readfirstlane(t >> 6);
  const int b  = bg * 64 + lane;
  const int o0 = w * 4;
  const int c0 = cq * 2;
  const int rbase = rseg * 9;

  float4 vf[2];
#pragma unroll
  for (int cc = 0; cc < 2; ++cc)
    vf[cc] = *(const float4*)(v + (size_t)b * SCO + (c0 + cc) * O_ + o0);

  const float4* xp = (const float4*)(x + ((size_t)b * R_ + rbase) * I_);
  float4 xa = xp[0], xb = xp[1];
  for (int rr = 0; rr < 9; ++rr) {
    const int r = rbase + rr;
    float4 na = xa, nb = xb;
    if (rr + 1 < 9) { na = xp[2 * (rr + 1)]; nb = xp[2 * (rr + 1) + 1]; }
#pragma unroll
    for (int cc = 0; cc < 2; ++cc) {
      const float* wr = W + (size_t)(r * C_ + c0 + cc) * 128 + o0 * 8;  // uniform
      float a;
      a = dot8v(wr,      xa, xb) * vf[cc].x;
      a = fmaf(dot8v(wr + 8,  xa, xb), vf[cc].y, a);
      a = fmaf(dot8v(wr + 16, xa, xb), vf[cc].z, a);
      a = fmaf(dot8v(wr + 24, xa, xb), vf[cc].w, a);
      a += __shfl_xor(a, 1);  a += __shfl_xor(a, 2);  a += __shfl_xor(a, 4);
      a += __shfl_xor(a, 8);  a += __shfl_xor(a, 16); a += __shfl_xor(a, 32);
      if (lane == 0) red[(rr * 2 + cc) * 4 + w] = a;
    }
    xa = na; xb = nb;
  }
  __syncthreads();
  if (t < 18) {
    float s = red[t * 4] + red[t * 4 + 1] + red[t * 4 + 2] + red[t * 4 + 3];
    int rr = t >> 1, cc = t & 1;
    bpart[((size_t)bg * R_ + (rbase + rr)) * C_ + c0 + cc] = s;
  }
}

// b_new = (first ? 0 : b_prev) + (sum_bg bpart)/256; cvec = softmax over r per c.
__global__ __launch_bounds__(256) void k_bc(const float* __restrict__ bpart,
                                            float* __restrict__ bvec,
                                            float* __restrict__ cvec, int first) {
  const int c = blockIdx.x;
  const int t = threadIdx.x;
  __shared__ float smx[4];
  __shared__ float sms[4];
  float bv[5];
  float mx = -3.402823466e38f;
#pragma unroll
  for (int k = 0; k < 5; ++k) {
    int r = t + k * 256;
    if (r < R_) {
      float s = bpart[(size_t)r * C_ + c]
              + bpart[((size_t)R_ + r) * C_ + c]
              + bpart[((size_t)2 * R_ + r) * C_ + c]
              + bpart[((size_t)3 * R_ + r) * C_ + c];
      float val = s * (1.0f / 256.0f);
      if (!first) val += bvec[r * C_ + c];
      bvec[r * C_ + c] = val;
      bv[k] = val;
      mx = fmaxf(mx, val);
    }
  }
  mx = fmaxf(mx, __shfl_xor(mx, 1));  mx = fmaxf(mx, __shfl_xor(mx, 2));
  mx = fmaxf(mx, __shfl_xor(mx, 4));  mx = fmaxf(mx, __shfl_xor(mx, 8));
  mx = fmaxf(mx, __shfl_xor(mx, 16)); mx = fmaxf(mx, __shfl_xor(mx, 32));
  if ((t & 63) == 0) smx[t >> 6] = mx;
  __syncthreads();
  float MX = fmaxf(fmaxf(smx[0], smx[1]), fmaxf(smx[2], smx[3]));
  float se = 0.0f;
  float ef[5];
#pragma unroll
  for (int k = 0; k < 5; ++k) {
    int r = t + k * 256;
    if (r < R_) { ef[k] = expf(bv[k] - MX); se += ef[k]; }
  }
  se += __shfl_xor(se, 1);  se += __shfl_xor(se, 2);  se += __shfl_xor(se, 4);
  se += __shfl_xor(se, 8);  se += __shfl_xor(se, 16); se += __shfl_xor(se, 32);
  if ((t & 63) == 0) sms[t >> 6] = se;
  __syncthreads();
  float inv = 1.0f / ((sms[0] + sms[1]) + (sms[2] + sms[3]));
#pragma unroll
  for (int k = 0; k < 5; ++k) {
    int r = t + k * 256;
    if (r < R_) cvec[r * C_ + c] = ef[k] * inv;
  }
}

extern "C" void kernel_launch(void* const* d_in, const int* in_sizes, int n_in,
                              void* d_out, int out_size, void* d_ws, size_t ws_size,
                              hipStream_t stream) {
  const float* x = (const float*)d_in[0];  // (B,R,I) fp32
  const float* W = (const float*)d_in[1];  // (R,C,O,I) fp32
  float* out = (float*)d_out;              // (B,C,O,1) fp32, NV elements
  float* ws = (float*)d_ws;

  // ws-adaptive segment count for k_s partials
  const long availf = (long)(ws_size / 4);
  const long fixedf = NV + 6L * (R_ * C_);   // v + bvec + cvec + bpart[4]
  long cap = (availf - fixedf) / NV;
  int nseg = 1;
  while (nseg * 2 <= 64 && (long)(nseg * 2) <= cap) nseg *= 2;

  float* partial = ws;
  float* v     = partial + (size_t)nseg * NV;
  float* bvec  = v + NV;
  float* cvec  = bvec + (R_ * C_);
  float* bpart = cvec + (R_ * C_);

  for (int it = 0; it < 3; ++it) {
    k_s<<<nseg * 20, 256, 0, stream>>>(x, W, cvec, partial, it > 0 ? 1 : 0, nseg);
    k_sv<<<NV / 256, 256, 0, stream>>>(partial, (it == 2) ? out : v, nseg);
    if (it < 2) {
      k_a<<<128 * 20, 256, 0, stream>>>(x, W, v, bpart);
      k_bc<<<C_, 256, 0, stream>>>(bpart, bvec, cvec, it == 0 ? 1 : 0);
    }
  }
}